// Round 2
// baseline (658.601 us; speedup 1.0000x reference)
//
#include <hip/hip_runtime.h>
#include <hip/hip_bf16.h>
#include <stdint.h>

#define GN 8192
#define GF 128
#define NEG_SLOPE 0.2f
#define BK 128
#define PST 136           // padded LDS row stride (bf16 elems): 272 B -> bank stride 4
#define BIGM 700.0f       // exp(-700) == 0.0f: masked entries vanish exactly

typedef __attribute__((ext_vector_type(8))) short bf16x8;
typedef __attribute__((ext_vector_type(4))) float f32x4;

__device__ __forceinline__ unsigned fkey(float f) {
    unsigned u = __float_as_uint(f);
    return (u & 0x80000000u) ? ~u : (u | 0x80000000u);
}
__device__ __forceinline__ float funkey(unsigned k) {
    unsigned b = (k & 0x80000000u) ? (k & 0x7FFFFFFFu) : ~k;
    return __uint_as_float(b);
}
__device__ __forceinline__ unsigned short bf16rne(float f) {
    unsigned u = __float_as_uint(f);
    return (unsigned short)((u + 0x7FFFu + ((u >> 16) & 1u)) >> 16);
}
// pack two fp32 -> two bf16 (round-half-up) in one v_perm
__device__ __forceinline__ unsigned packbf(float lo, float hi) {
    return __builtin_amdgcn_perm(__float_as_uint(hi) + 0x8000u,
                                 __float_as_uint(lo) + 0x8000u, 0x07060302u);
}

// K1: x' = x@W + b (fp32); writes XPT = x'^T as bf16 [GF][GN], s_src, s_dst. NO atomics.
__global__ __launch_bounds__(256) void gat_k1(
    const float* __restrict__ x, const float* __restrict__ w,
    const float* __restrict__ bias, const float* __restrict__ phi,
    unsigned short* __restrict__ xpt, float* __restrict__ s_src,
    float* __restrict__ s_dst)
{
    __shared__ float Xl[16][132];
    __shared__ float Wl[32][132];
    __shared__ unsigned short TR[128][24];
    const int tid = threadIdx.x;
    const int i0 = blockIdx.x * 16;

    #pragma unroll
    for (int q = 0; q < 2; q++) {                 // stage 16x128 x tile
        int flat = (q * 256 + tid) * 4;
        int r = flat >> 7, c = flat & 127;
        *(float4*)&Xl[r][c] = *(const float4*)&x[(size_t)(i0 + r) * GF + c];
    }

    const int rid = tid >> 5;          // 0..7 -> rows 2rid, 2rid+1
    const int c0  = (tid & 31) * 4;    // 4 consecutive features

    float acc[2][4] = {};
    for (int kc = 0; kc < 4; kc++) {   // W staged in 32-row chunks (16.9 KB)
        __syncthreads();
        #pragma unroll
        for (int q = 0; q < 4; q++) {
            int flat = (q * 256 + tid) * 4;
            int kk = flat >> 7, c = flat & 127;
            *(float4*)&Wl[kk][c] = *(const float4*)&w[(size_t)(kc * 32 + kk) * GF + c];
        }
        __syncthreads();
        #pragma unroll
        for (int k = 0; k < 32; k++) {
            float4 wv = *(const float4*)&Wl[k][c0];
            #pragma unroll
            for (int m = 0; m < 2; m++) {
                float xv = Xl[rid * 2 + m][kc * 32 + k];
                acc[m][0] = fmaf(xv, wv.x, acc[m][0]);
                acc[m][1] = fmaf(xv, wv.y, acc[m][1]);
                acc[m][2] = fmaf(xv, wv.z, acc[m][2]);
                acc[m][3] = fmaf(xv, wv.w, acc[m][3]);
            }
        }
    }

    float b4[4], p1[4], p2[4];
    #pragma unroll
    for (int q = 0; q < 4; q++) {
        b4[q] = bias[c0 + q];
        p1[q] = phi[c0 + q];
        p2[q] = phi[GF + c0 + q];
    }
    #pragma unroll
    for (int m = 0; m < 2; m++) {
        float ps = 0.f, pd = 0.f;
        #pragma unroll
        for (int q = 0; q < 4; q++) {
            float v = acc[m][q] + b4[q];
            ps = fmaf(v, p1[q], ps);
            pd = fmaf(v, p2[q], pd);
            TR[c0 + q][rid * 2 + m] = bf16rne(v);   // LDS transpose staging
        }
        #pragma unroll
        for (int s = 16; s >= 1; s >>= 1) {         // reduce across the 32-thread row group
            ps += __shfl_xor(ps, s, 64);
            pd += __shfl_xor(pd, s, 64);
        }
        if ((tid & 31) == 0) {
            s_src[i0 + rid * 2 + m] = ps;
            s_dst[i0 + rid * 2 + m] = pd;
        }
    }
    __syncthreads();
    {   // coalesced transposed store: thread pair per feature row
        const int f = tid >> 1, part = (tid & 1) * 8;
        uint2 lo = *(const uint2*)&TR[f][part];
        uint2 hi = *(const uint2*)&TR[f][part + 4];
        uint4 o; o.x = lo.x; o.y = lo.y; o.z = hi.x; o.w = hi.y;
        *(uint4*)&xpt[(size_t)f * GN + i0 + part] = o;
    }
}

// K1b: D = max(s_dst). 8 blocks -> only 8 same-address atomics.
__global__ __launch_bounds__(256) void gat_k1b(
    const float* __restrict__ s_dst, unsigned* __restrict__ Dkey)
{
    __shared__ float sm[4];
    const int tid = threadIdx.x;
    const int idx = (blockIdx.x * 256 + tid) * 4;
    float4 v = *(const float4*)&s_dst[idx];
    float m = fmaxf(fmaxf(v.x, v.y), fmaxf(v.z, v.w));
    #pragma unroll
    for (int s = 32; s >= 1; s >>= 1) m = fmaxf(m, __shfl_xor(m, s, 64));
    if ((tid & 63) == 0) sm[tid >> 6] = m;
    __syncthreads();
    if (tid == 0) {
        m = fmaxf(fmaxf(sm[0], sm[1]), fmaxf(sm[2], sm[3]));
        atomicMax(Dkey, fkey(m));
    }
}

// K2: flash-style dense GAT row-softmax + MFMA P@x'.
// Block = 16 rows, 256 threads (4 waves, wave w owns features [32w,32w+32)).
__global__ __launch_bounds__(256) void gat_k2(
    const float* __restrict__ adj, const unsigned short* __restrict__ xpt,
    const float* __restrict__ s_src, const float* __restrict__ s_dst,
    const unsigned* __restrict__ Dkey, float* __restrict__ out)
{
    __shared__ unsigned short Pl[16 * PST];    // P tile, bf16, padded
    __shared__ unsigned short Xl[128 * PST];   // x' K-slice (B operand), padded
    __shared__ float Zs[16];

    const int tid = threadIdx.x;
    const int wave = tid >> 6, lane = tid & 63;
    const int i0 = blockIdx.x * 16;
    const int rg = tid >> 5;             // 0..7: rows rg and rg+8
    const int cls = (tid & 31) * 4;      // 4 consecutive cols within chunk
    const int m16 = lane & 15, q4 = lane >> 4;
    const int xf = tid >> 4;             // XPT staging: row group
    const int xko = (tid & 15) * 8;      // 8 bf16 = 16 B per lane

    const float D = funkey(*Dkey);
    const float si0 = s_src[i0 + rg];
    const float si1 = s_src[i0 + rg + 8];
    float t0 = si0 + D, t1 = si1 + D;
    const float mneg0 = -fmaxf(t0, NEG_SLOPE * t0);   // -Mi (upper bound of row max)
    const float mneg1 = -fmaxf(t1, NEG_SLOPE * t1);
    const float base0 = mneg0 - BIGM;
    const float base1 = mneg1 - BIGM;
    const int idiag0 = i0 + rg, idiag1 = i0 + rg + 8;

    const float* arow0 = adj + (size_t)(i0 + rg) * GN;
    const float* arow1 = adj + (size_t)(i0 + rg + 8) * GN;

    const int aoff  = m16 * PST + q4 * 8;             // A-frag LDS offset (elems)
    const int boff0 = (wave * 32 + m16) * PST + q4 * 8;
    const int boff1 = boff0 + 16 * PST;

    f32x4 acc0 = {0.f, 0.f, 0.f, 0.f};
    f32x4 acc1 = {0.f, 0.f, 0.f, 0.f};
    float z0 = 0.f, z1 = 0.f;

    #pragma unroll 1
    for (int ck = 0; ck < GN / BK; ck++) {
        const int jb = ck * BK + cls;
        float4 a0  = *(const float4*)(arow0 + jb);
        float4 a1  = *(const float4*)(arow1 + jb);
        float4 sd4 = *(const float4*)(s_dst + jb);
        uint4 xg[8];
        #pragma unroll
        for (int j = 0; j < 8; j++)
            xg[j] = *(const uint4*)&xpt[(size_t)(j * 16 + xf) * GN + ck * BK + xko];

        float p0[4], p1v[4];
        #pragma unroll
        for (int q = 0; q < 4; q++) {
            const float sd = (&sd4.x)[q];
            float t, lr, z;
            t = si0 + sd; lr = fmaxf(t, NEG_SLOPE * t);
            z = fmaf((&a0.x)[q], BIGM, lr + base0);
            if (jb + q == idiag0) z = lr + mneg0;     // self-loop always kept
            p0[q] = __expf(z);
            t = si1 + sd; lr = fmaxf(t, NEG_SLOPE * t);
            z = fmaf((&a1.x)[q], BIGM, lr + base1);
            if (jb + q == idiag1) z = lr + mneg1;
            p1v[q] = __expf(z);
        }
        z0 += p0[0] + p0[1] + p0[2] + p0[3];
        z1 += p1v[0] + p1v[1] + p1v[2] + p1v[3];

        __syncthreads();   // previous MFMA phase done reading LDS
        *(uint2*)&Pl[rg * PST + cls] =
            make_uint2(packbf(p0[0], p0[1]), packbf(p0[2], p0[3]));
        *(uint2*)&Pl[(rg + 8) * PST + cls] =
            make_uint2(packbf(p1v[0], p1v[1]), packbf(p1v[2], p1v[3]));
        #pragma unroll
        for (int j = 0; j < 8; j++)
            *(uint4*)&Xl[(j * 16 + xf) * PST + xko] = xg[j];
        __syncthreads();

        #pragma unroll
        for (int ks = 0; ks < 4; ks++) {
            bf16x8 af = *(const bf16x8*)&Pl[aoff + ks * 32];
            bf16x8 b0 = *(const bf16x8*)&Xl[boff0 + ks * 32];
            bf16x8 b1 = *(const bf16x8*)&Xl[boff1 + ks * 32];
            acc0 = __builtin_amdgcn_mfma_f32_16x16x32_bf16(af, b0, acc0, 0, 0, 0);
            acc1 = __builtin_amdgcn_mfma_f32_16x16x32_bf16(af, b1, acc1, 0, 0, 0);
        }
    }

    #pragma unroll
    for (int s = 1; s <= 16; s <<= 1) {   // reduce Z across 32-thread row group
        z0 += __shfl_xor(z0, s, 64);
        z1 += __shfl_xor(z1, s, 64);
    }
    if ((tid & 31) == 0) { Zs[rg] = z0; Zs[rg + 8] = z1; }
    __syncthreads();

    #pragma unroll
    for (int v = 0; v < 4; v++) {         // C layout: row=(lane>>4)*4+v, col=lane&15
        const int row = q4 * 4 + v;
        const float invz = 1.0f / Zs[row];
        out[(size_t)(i0 + row) * GF + wave * 32 + m16]      = acc0[v] * invz;
        out[(size_t)(i0 + row) * GF + wave * 32 + 16 + m16] = acc1[v] * invz;
    }
}

extern "C" void kernel_launch(void* const* d_in, const int* in_sizes, int n_in,
                              void* d_out, int out_size, void* d_ws, size_t ws_size,
                              hipStream_t stream)
{
    (void)in_sizes; (void)n_in; (void)out_size; (void)ws_size;
    const float* adj  = (const float*)d_in[0];
    const float* x    = (const float*)d_in[1];
    const float* w    = (const float*)d_in[2];
    const float* bias = (const float*)d_in[3];
    const float* phi  = (const float*)d_in[4];
    float* out = (float*)d_out;

    char* ws = (char*)d_ws;
    unsigned short* xpt = (unsigned short*)ws;             // 2 MB bf16 x'^T [GF][GN]
    float* s_src = (float*)(ws + (size_t)GF * GN * 2);     // 32 KB
    float* s_dst = s_src + GN;                             // 32 KB
    unsigned* Dkey = (unsigned*)(s_dst + GN);              // 4 B

    hipMemsetAsync(Dkey, 0, sizeof(unsigned), stream);
    gat_k1 <<<GN / 16, 256, 0, stream>>>(x, w, bias, phi, xpt, s_src, s_dst);
    gat_k1b<<<8, 256, 0, stream>>>(s_dst, Dkey);
    gat_k2 <<<GN / 16, 256, 0, stream>>>(adj, xpt, s_src, s_dst, Dkey, out);
}

// Round 3
// 546.530 us; speedup vs baseline: 1.2051x; 1.2051x over previous
//
#include <hip/hip_runtime.h>
#include <hip/hip_bf16.h>
#include <stdint.h>

#define GN 8192
#define GF 128
#define NEG_SLOPE 0.2f
#define BIGM 700.0f       // exp(-700) == 0.0f: masked entries vanish exactly

typedef __attribute__((ext_vector_type(8))) short bf16x8;
typedef __attribute__((ext_vector_type(4))) float f32x4;

__device__ __forceinline__ unsigned fkey(float f) {
    unsigned u = __float_as_uint(f);
    return (u & 0x80000000u) ? ~u : (u | 0x80000000u);
}
__device__ __forceinline__ float funkey(unsigned k) {
    unsigned b = (k & 0x80000000u) ? (k & 0x7FFFFFFFu) : ~k;
    return __uint_as_float(b);
}
__device__ __forceinline__ unsigned short bf16rne(float f) {
    unsigned u = __float_as_uint(f);
    return (unsigned short)((u + 0x7FFFu + ((u >> 16) & 1u)) >> 16);
}
// pack two fp32 -> two bf16 (round-half-up) in one v_perm
__device__ __forceinline__ unsigned packbf(float lo, float hi) {
    return __builtin_amdgcn_perm(__float_as_uint(hi) + 0x8000u,
                                 __float_as_uint(lo) + 0x8000u, 0x07060302u);
}

// K1: x' = x@W + b (fp32); writes XPT = x'^T as bf16 [GF][GN], s_src, s_dst. NO atomics.
__global__ __launch_bounds__(256) void gat_k1(
    const float* __restrict__ x, const float* __restrict__ w,
    const float* __restrict__ bias, const float* __restrict__ phi,
    unsigned short* __restrict__ xpt, float* __restrict__ s_src,
    float* __restrict__ s_dst)
{
    __shared__ float Xl[16][132];
    __shared__ float Wl[32][132];
    __shared__ unsigned short TR[128][24];
    const int tid = threadIdx.x;
    const int i0 = blockIdx.x * 16;

    #pragma unroll
    for (int q = 0; q < 2; q++) {                 // stage 16x128 x tile
        int flat = (q * 256 + tid) * 4;
        int r = flat >> 7, c = flat & 127;
        *(float4*)&Xl[r][c] = *(const float4*)&x[(size_t)(i0 + r) * GF + c];
    }

    const int rid = tid >> 5;          // 0..7 -> rows 2rid, 2rid+1
    const int c0  = (tid & 31) * 4;    // 4 consecutive features

    float acc[2][4] = {};
    for (int kc = 0; kc < 4; kc++) {   // W staged in 32-row chunks
        __syncthreads();
        #pragma unroll
        for (int q = 0; q < 4; q++) {
            int flat = (q * 256 + tid) * 4;
            int kk = flat >> 7, c = flat & 127;
            *(float4*)&Wl[kk][c] = *(const float4*)&w[(size_t)(kc * 32 + kk) * GF + c];
        }
        __syncthreads();
        #pragma unroll
        for (int k = 0; k < 32; k++) {
            float4 wv = *(const float4*)&Wl[k][c0];
            #pragma unroll
            for (int m = 0; m < 2; m++) {
                float xv = Xl[rid * 2 + m][kc * 32 + k];
                acc[m][0] = fmaf(xv, wv.x, acc[m][0]);
                acc[m][1] = fmaf(xv, wv.y, acc[m][1]);
                acc[m][2] = fmaf(xv, wv.z, acc[m][2]);
                acc[m][3] = fmaf(xv, wv.w, acc[m][3]);
            }
        }
    }

    float b4[4], p1[4], p2[4];
    #pragma unroll
    for (int q = 0; q < 4; q++) {
        b4[q] = bias[c0 + q];
        p1[q] = phi[c0 + q];
        p2[q] = phi[GF + c0 + q];
    }
    #pragma unroll
    for (int m = 0; m < 2; m++) {
        float ps = 0.f, pd = 0.f;
        #pragma unroll
        for (int q = 0; q < 4; q++) {
            float v = acc[m][q] + b4[q];
            ps = fmaf(v, p1[q], ps);
            pd = fmaf(v, p2[q], pd);
            TR[c0 + q][rid * 2 + m] = bf16rne(v);   // LDS transpose staging
        }
        #pragma unroll
        for (int s = 16; s >= 1; s >>= 1) {
            ps += __shfl_xor(ps, s, 64);
            pd += __shfl_xor(pd, s, 64);
        }
        if ((tid & 31) == 0) {
            s_src[i0 + rid * 2 + m] = ps;
            s_dst[i0 + rid * 2 + m] = pd;
        }
    }
    __syncthreads();
    {   // coalesced transposed store
        const int f = tid >> 1, part = (tid & 1) * 8;
        uint2 lo = *(const uint2*)&TR[f][part];
        uint2 hi = *(const uint2*)&TR[f][part + 4];
        uint4 o; o.x = lo.x; o.y = lo.y; o.z = hi.x; o.w = hi.y;
        *(uint4*)&xpt[(size_t)f * GN + i0 + part] = o;
    }
}

// K1b: D = max(s_dst). 8 blocks -> only 8 same-address atomics.
__global__ __launch_bounds__(256) void gat_k1b(
    const float* __restrict__ s_dst, unsigned* __restrict__ Dkey)
{
    __shared__ float sm[4];
    const int tid = threadIdx.x;
    const int idx = (blockIdx.x * 256 + tid) * 4;
    float4 v = *(const float4*)&s_dst[idx];
    float m = fmaxf(fmaxf(v.x, v.y), fmaxf(v.z, v.w));
    #pragma unroll
    for (int s = 32; s >= 1; s >>= 1) m = fmaxf(m, __shfl_xor(m, s, 64));
    if ((tid & 63) == 0) sm[tid >> 6] = m;
    __syncthreads();
    if (tid == 0) {
        m = fmaxf(fmaxf(sm[0], sm[1]), fmaxf(sm[2], sm[3]));
        atomicMax(Dkey, fkey(m));
    }
}

// K2: barrier-free flash GAT. Block = 16 rows, 4 waves; wave w owns chunks 4t+w.
// A-frag (P) computed in-register in MFMA A-layout: lane(m16,q4) handles
// row i0+m16, cols j0..j0+7. B-frag loaded straight from global xpt (16B/lane).
// No LDS / no __syncthreads in the K-loop. Epilogue: cross-wave LDS reduce.
__global__ __launch_bounds__(256, 3) void gat_k2(
    const float* __restrict__ adj, const unsigned short* __restrict__ xpt,
    const float* __restrict__ s_src, const float* __restrict__ s_dst,
    const unsigned* __restrict__ Dkey, float* __restrict__ out)
{
    __shared__ float Ol[4][16][132];
    __shared__ float Zl[4][16];

    const int tid  = threadIdx.x;
    const int wave = tid >> 6, lane = tid & 63;
    const int m16  = lane & 15, q4 = lane >> 4;
    const int i0   = blockIdx.x * 16;
    const int irow = i0 + m16;

    const float D  = funkey(*Dkey);
    const float si = s_src[irow];
    const float t0 = si + D;
    const float mneg = -fmaxf(t0, NEG_SLOPE * t0);   // -Mi >= -rowmax bound
    const float base = mneg - BIGM;
    const int ckdiag = i0 >> 7;          // the one 128-col chunk holding all 16 diagonals

    const float* arow = adj + (size_t)irow * GN;

    f32x4 acc[8];
    #pragma unroll
    for (int fg = 0; fg < 8; fg++) acc[fg] = (f32x4){0.f, 0.f, 0.f, 0.f};
    float z = 0.f;

    #pragma unroll 1
    for (int t16 = 0; t16 < 16; t16++) {
        const int ck = t16 * 4 + wave;
        const int cbase = ck * 128;
        #pragma unroll
        for (int ks = 0; ks < 4; ks++) {
            const int j0 = cbase + ks * 32 + q4 * 8;
            float4 a0 = *(const float4*)(arow + j0);
            float4 a1 = *(const float4*)(arow + j0 + 4);
            float4 d0 = *(const float4*)(s_dst + j0);
            float4 d1 = *(const float4*)(s_dst + j0 + 4);

            float p[8];
            #pragma unroll
            for (int q = 0; q < 8; q++) {
                const float sd = (q < 4) ? (&d0.x)[q] : (&d1.x)[q - 4];
                const float aq = (q < 4) ? (&a0.x)[q] : (&a1.x)[q - 4];
                const float tt = si + sd;
                const float lr = fmaxf(tt, NEG_SLOPE * tt);
                float zz = fmaf(aq, BIGM, lr + base);
                if (ck == ckdiag && (j0 + q) == irow) zz = lr + mneg; // self-loop
                p[q] = __expf(zz);
                z += p[q];
            }

            union { unsigned u[4]; bf16x8 v; } au;
            au.u[0] = packbf(p[0], p[1]);
            au.u[1] = packbf(p[2], p[3]);
            au.u[2] = packbf(p[4], p[5]);
            au.u[3] = packbf(p[6], p[7]);
            const bf16x8 af = au.v;

            #pragma unroll
            for (int fg = 0; fg < 8; fg++) {
                const bf16x8 bf =
                    *(const bf16x8*)&xpt[(size_t)(fg * 16 + m16) * GN + j0];
                acc[fg] = __builtin_amdgcn_mfma_f32_16x16x32_bf16(af, bf, acc[fg], 0, 0, 0);
            }
        }
    }

    // C layout: col = lane&15, row = q4*4 + v
    #pragma unroll
    for (int fg = 0; fg < 8; fg++)
        #pragma unroll
        for (int v = 0; v < 4; v++)
            Ol[wave][q4 * 4 + v][fg * 16 + m16] = acc[fg][v];

    z += __shfl_xor(z, 16, 64);      // reduce over q4 (lanes sharing m16)
    z += __shfl_xor(z, 32, 64);
    if (lane < 16) Zl[wave][m16] = z;
    __syncthreads();

    {   // cross-wave reduce + normalize: thread -> row tid>>4, 8 cols
        const int r = tid >> 4, c = (tid & 15) * 8;
        const float invz = 1.0f / (Zl[0][r] + Zl[1][r] + Zl[2][r] + Zl[3][r]);
        f32x4 s0 = {0.f, 0.f, 0.f, 0.f}, s1 = {0.f, 0.f, 0.f, 0.f};
        #pragma unroll
        for (int wv = 0; wv < 4; wv++) {
            s0 += *(const f32x4*)&Ol[wv][r][c];
            s1 += *(const f32x4*)&Ol[wv][r][c + 4];
        }
        s0 *= invz; s1 *= invz;
        *(f32x4*)&out[(size_t)(i0 + r) * GF + c]     = s0;
        *(f32x4*)&out[(size_t)(i0 + r) * GF + c + 4] = s1;
    }
}

extern "C" void kernel_launch(void* const* d_in, const int* in_sizes, int n_in,
                              void* d_out, int out_size, void* d_ws, size_t ws_size,
                              hipStream_t stream)
{
    (void)in_sizes; (void)n_in; (void)out_size; (void)ws_size;
    const float* adj  = (const float*)d_in[0];
    const float* x    = (const float*)d_in[1];
    const float* w    = (const float*)d_in[2];
    const float* bias = (const float*)d_in[3];
    const float* phi  = (const float*)d_in[4];
    float* out = (float*)d_out;

    char* ws = (char*)d_ws;
    unsigned short* xpt = (unsigned short*)ws;             // 2 MB bf16 x'^T [GF][GN]
    float* s_src = (float*)(ws + (size_t)GF * GN * 2);     // 32 KB
    float* s_dst = s_src + GN;                             // 32 KB
    unsigned* Dkey = (unsigned*)(s_dst + GN);              // 4 B

    hipMemsetAsync(Dkey, 0, sizeof(unsigned), stream);
    gat_k1 <<<GN / 16, 256, 0, stream>>>(x, w, bias, phi, xpt, s_src, s_dst);
    gat_k1b<<<8, 256, 0, stream>>>(s_dst, Dkey);
    gat_k2 <<<GN / 16, 256, 0, stream>>>(adj, xpt, s_src, s_dst, Dkey, out);
}

// Round 4
// 450.516 us; speedup vs baseline: 1.4619x; 1.2131x over previous
//
#include <hip/hip_runtime.h>
#include <hip/hip_bf16.h>
#include <stdint.h>

#define GN 8192
#define GF 128
#define NEG_SLOPE 0.2f
#define BIGM 700.0f       // exp(-700) == 0.0f: masked entries vanish exactly

typedef __attribute__((ext_vector_type(8))) short bf16x8;
typedef __attribute__((ext_vector_type(4))) float f32x4;

__device__ __forceinline__ unsigned fkey(float f) {
    unsigned u = __float_as_uint(f);
    return (u & 0x80000000u) ? ~u : (u | 0x80000000u);
}
__device__ __forceinline__ float funkey(unsigned k) {
    unsigned b = (k & 0x80000000u) ? (k & 0x7FFFFFFFu) : ~k;
    return __uint_as_float(b);
}
__device__ __forceinline__ unsigned short bf16rne(float f) {
    unsigned u = __float_as_uint(f);
    return (unsigned short)((u + 0x7FFFu + ((u >> 16) & 1u)) >> 16);
}
// pack two fp32 -> two bf16 (round-half-up) in one v_perm
__device__ __forceinline__ unsigned packbf(float lo, float hi) {
    return __builtin_amdgcn_perm(__float_as_uint(hi) + 0x8000u,
                                 __float_as_uint(lo) + 0x8000u, 0x07060302u);
}

// K1: x' = x@W + b (fp32); writes XPT = x'^T as bf16 [GF][GN], s_src, s_dst.
__global__ __launch_bounds__(256) void gat_k1(
    const float* __restrict__ x, const float* __restrict__ w,
    const float* __restrict__ bias, const float* __restrict__ phi,
    unsigned short* __restrict__ xpt, float* __restrict__ s_src,
    float* __restrict__ s_dst)
{
    __shared__ float Xl[16][132];
    __shared__ float Wl[32][132];
    __shared__ unsigned short TR[128][24];
    const int tid = threadIdx.x;
    const int i0 = blockIdx.x * 16;

    #pragma unroll
    for (int q = 0; q < 2; q++) {                 // stage 16x128 x tile
        int flat = (q * 256 + tid) * 4;
        int r = flat >> 7, c = flat & 127;
        *(float4*)&Xl[r][c] = *(const float4*)&x[(size_t)(i0 + r) * GF + c];
    }

    const int rid = tid >> 5;          // 0..7 -> rows 2rid, 2rid+1
    const int c0  = (tid & 31) * 4;    // 4 consecutive features

    float acc[2][4] = {};
    for (int kc = 0; kc < 4; kc++) {   // W staged in 32-row chunks
        __syncthreads();
        #pragma unroll
        for (int q = 0; q < 4; q++) {
            int flat = (q * 256 + tid) * 4;
            int kk = flat >> 7, c = flat & 127;
            *(float4*)&Wl[kk][c] = *(const float4*)&w[(size_t)(kc * 32 + kk) * GF + c];
        }
        __syncthreads();
        #pragma unroll
        for (int k = 0; k < 32; k++) {
            float4 wv = *(const float4*)&Wl[k][c0];
            #pragma unroll
            for (int m = 0; m < 2; m++) {
                float xv = Xl[rid * 2 + m][kc * 32 + k];
                acc[m][0] = fmaf(xv, wv.x, acc[m][0]);
                acc[m][1] = fmaf(xv, wv.y, acc[m][1]);
                acc[m][2] = fmaf(xv, wv.z, acc[m][2]);
                acc[m][3] = fmaf(xv, wv.w, acc[m][3]);
            }
        }
    }

    float b4[4], p1[4], p2[4];
    #pragma unroll
    for (int q = 0; q < 4; q++) {
        b4[q] = bias[c0 + q];
        p1[q] = phi[c0 + q];
        p2[q] = phi[GF + c0 + q];
    }
    #pragma unroll
    for (int m = 0; m < 2; m++) {
        float ps = 0.f, pd = 0.f;
        #pragma unroll
        for (int q = 0; q < 4; q++) {
            float v = acc[m][q] + b4[q];
            ps = fmaf(v, p1[q], ps);
            pd = fmaf(v, p2[q], pd);
            TR[c0 + q][rid * 2 + m] = bf16rne(v);   // LDS transpose staging
        }
        #pragma unroll
        for (int s = 16; s >= 1; s >>= 1) {
            ps += __shfl_xor(ps, s, 64);
            pd += __shfl_xor(pd, s, 64);
        }
        if ((tid & 31) == 0) {
            s_src[i0 + rid * 2 + m] = ps;
            s_dst[i0 + rid * 2 + m] = pd;
        }
    }
    __syncthreads();
    {   // coalesced transposed store
        const int f = tid >> 1, part = (tid & 1) * 8;
        uint2 lo = *(const uint2*)&TR[f][part];
        uint2 hi = *(const uint2*)&TR[f][part + 4];
        uint4 o; o.x = lo.x; o.y = lo.y; o.z = hi.x; o.w = hi.y;
        *(uint4*)&xpt[(size_t)f * GN + i0 + part] = o;
    }
}

// K1b: D = max(s_dst). 8 blocks -> only 8 same-address atomics.
__global__ __launch_bounds__(256) void gat_k1b(
    const float* __restrict__ s_dst, unsigned* __restrict__ Dkey)
{
    __shared__ float sm[4];
    const int tid = threadIdx.x;
    const int idx = (blockIdx.x * 256 + tid) * 4;
    float4 v = *(const float4*)&s_dst[idx];
    float m = fmaxf(fmaxf(v.x, v.y), fmaxf(v.z, v.w));
    #pragma unroll
    for (int s = 32; s >= 1; s >>= 1) m = fmaxf(m, __shfl_xor(m, s, 64));
    if ((tid & 63) == 0) sm[tid >> 6] = m;
    __syncthreads();
    if (tid == 0) {
        m = fmaxf(fmaxf(sm[0], sm[1]), fmaxf(sm[2], sm[3]));
        atomicMax(Dkey, fkey(m));
    }
}

// K2: barrier-free flash GAT, explicit depth-1 prefetch for MLP.
// Block = 16 rows, 4 waves; wave w owns chunks 4t+w. s_dst staged in LDS.
// A-frag (P) computed in-register in MFMA A-layout; B-frag straight from xpt.
__global__ __launch_bounds__(256, 2) void gat_k2(
    const float* __restrict__ adj, const unsigned short* __restrict__ xpt,
    const float* __restrict__ s_src, const float* __restrict__ s_dst,
    const unsigned* __restrict__ Dkey, float* __restrict__ out)
{
    __shared__ float smem[8448];     // K-loop: s_dst copy (8192 f); epilogue: Ol[4][16][132]
    __shared__ float Zl[4][16];

    const int tid  = threadIdx.x;
    const int wave = tid >> 6, lane = tid & 63;
    const int m16  = lane & 15, q4 = lane >> 4;
    const int i0   = blockIdx.x * 16;
    const int irow = i0 + m16;

    #pragma unroll
    for (int s = 0; s < 8; s++) {    // stage all of s_dst into LDS (32 KB)
        const int idx = (s * 256 + tid) * 4;
        *(float4*)&smem[idx] = *(const float4*)&s_dst[idx];
    }

    const float D  = funkey(*Dkey);
    const float si = s_src[irow];
    const float t0 = si + D;
    const float mneg = -fmaxf(t0, NEG_SLOPE * t0);   // -Mi >= -(row max) bound
    const float base = mneg - BIGM;
    const int ckdiag = i0 >> 7;      // 128-col chunk holding this block's diagonals

    const float* arow = adj + (size_t)irow * GN;
    const unsigned short* xrow = xpt + (size_t)m16 * GN;  // + fg*16*GN per frag

    f32x4 acc[8];
    #pragma unroll
    for (int fg = 0; fg < 8; fg++) acc[fg] = (f32x4){0.f, 0.f, 0.f, 0.f};
    float z = 0.f;

    __syncthreads();                 // s_dst LDS visible to all waves

    // prologue: adj prefetch for chunk (t16=0)
    float4 apf[8];
    {
        const int cb0 = wave * 128;
        #pragma unroll
        for (int h = 0; h < 8; h++)
            apf[h] = *(const float4*)(arow + cb0 + (h >> 1) * 32 + q4 * 8 + (h & 1) * 4);
    }

    #pragma unroll 1
    for (int t16 = 0; t16 < 16; t16++) {
        const int ck = t16 * 4 + wave;
        const int cbase = ck * 128;
        const bool hasdiag = (ck == ckdiag);

        // ---- phase 1: P tile (A-frags) from prefetched adj + LDS s_dst ----
        bf16x8 af[4];
        #pragma unroll
        for (int ks = 0; ks < 4; ks++) {
            const int j0 = cbase + ks * 32 + q4 * 8;
            const float4 a0 = apf[ks * 2], a1 = apf[ks * 2 + 1];
            const float4 d0 = *(const float4*)&smem[j0 - cbase + cbase]; // LDS @ j0
            const float4 d1 = *(const float4*)&smem[j0 + 4];
            float p[8];
            #pragma unroll
            for (int q = 0; q < 8; q++) {
                const float sd = (q < 4) ? (&d0.x)[q] : (&d1.x)[q - 4];
                const float aq = (q < 4) ? (&a0.x)[q] : (&a1.x)[q - 4];
                const float tt = si + sd;
                const float lr = fmaxf(tt, NEG_SLOPE * tt);
                float zz = fmaf(aq, BIGM, lr + base);
                if (hasdiag && (j0 + q) == irow) zz = lr + mneg;  // self-loop
                p[q] = __expf(zz);
                z += p[q];
            }
            union { unsigned u[4]; bf16x8 v; } au;
            au.u[0] = packbf(p[0], p[1]);
            au.u[1] = packbf(p[2], p[3]);
            au.u[2] = packbf(p[4], p[5]);
            au.u[3] = packbf(p[6], p[7]);
            af[ks] = au.v;
        }

        // ---- phase 2: issue next chunk's adj loads (in flight during MFMA) ----
        if (t16 < 15) {
            const int nbase = (t16 * 4 + 4 + wave) * 128;
            #pragma unroll
            for (int h = 0; h < 8; h++)
                apf[h] = *(const float4*)(arow + nbase + (h >> 1) * 32 + q4 * 8 + (h & 1) * 4);
        }

        // ---- phase 3: MFMA with depth-1 B-frag prefetch ----
        bf16x8 bcur[8];
        #pragma unroll
        for (int fg = 0; fg < 8; fg++)
            bcur[fg] = *(const bf16x8*)&xrow[(size_t)(fg * 16) * GN + cbase + q4 * 8];
        #pragma unroll
        for (int ks = 0; ks < 4; ks++) {
            bf16x8 bnxt[8];
            if (ks < 3) {
                #pragma unroll
                for (int fg = 0; fg < 8; fg++)
                    bnxt[fg] = *(const bf16x8*)&xrow[(size_t)(fg * 16) * GN + cbase + (ks + 1) * 32 + q4 * 8];
            }
            #pragma unroll
            for (int fg = 0; fg < 8; fg++)
                acc[fg] = __builtin_amdgcn_mfma_f32_16x16x32_bf16(af[ks], bcur[fg], acc[fg], 0, 0, 0);
            if (ks < 3) {
                #pragma unroll
                for (int fg = 0; fg < 8; fg++) bcur[fg] = bnxt[fg];
            }
        }
    }

    __syncthreads();                 // all waves done reading s_dst LDS
    // epilogue: reuse smem as Ol[4][16][132]; C layout col=lane&15, row=q4*4+v
    #pragma unroll
    for (int fg = 0; fg < 8; fg++)
        #pragma unroll
        for (int v = 0; v < 4; v++)
            smem[(wave * 16 + q4 * 4 + v) * 132 + fg * 16 + m16] = acc[fg][v];

    z += __shfl_xor(z, 16, 64);      // reduce over q4 (lanes sharing m16)
    z += __shfl_xor(z, 32, 64);
    if (lane < 16) Zl[wave][m16] = z;
    __syncthreads();

    {   // cross-wave reduce + normalize: thread -> row tid>>4, 8 cols
        const int r = tid >> 4, c = (tid & 15) * 8;
        const float invz = 1.0f / (Zl[0][r] + Zl[1][r] + Zl[2][r] + Zl[3][r]);
        f32x4 s0 = {0.f, 0.f, 0.f, 0.f}, s1 = {0.f, 0.f, 0.f, 0.f};
        #pragma unroll
        for (int wv = 0; wv < 4; wv++) {
            s0 += *(const f32x4*)&smem[(wv * 16 + r) * 132 + c];
            s1 += *(const f32x4*)&smem[(wv * 16 + r) * 132 + c + 4];
        }
        s0 *= invz; s1 *= invz;
        *(f32x4*)&out[(size_t)(i0 + r) * GF + c]     = s0;
        *(f32x4*)&out[(size_t)(i0 + r) * GF + c + 4] = s1;
    }
}

extern "C" void kernel_launch(void* const* d_in, const int* in_sizes, int n_in,
                              void* d_out, int out_size, void* d_ws, size_t ws_size,
                              hipStream_t stream)
{
    (void)in_sizes; (void)n_in; (void)out_size; (void)ws_size;
    const float* adj  = (const float*)d_in[0];
    const float* x    = (const float*)d_in[1];
    const float* w    = (const float*)d_in[2];
    const float* bias = (const float*)d_in[3];
    const float* phi  = (const float*)d_in[4];
    float* out = (float*)d_out;

    char* ws = (char*)d_ws;
    unsigned short* xpt = (unsigned short*)ws;             // 2 MB bf16 x'^T [GF][GN]
    float* s_src = (float*)(ws + (size_t)GF * GN * 2);     // 32 KB
    float* s_dst = s_src + GN;                             // 32 KB
    unsigned* Dkey = (unsigned*)(s_dst + GN);              // 4 B

    hipMemsetAsync(Dkey, 0, sizeof(unsigned), stream);
    gat_k1 <<<GN / 16, 256, 0, stream>>>(x, w, bias, phi, xpt, s_src, s_dst);
    gat_k1b<<<8, 256, 0, stream>>>(s_dst, Dkey);
    gat_k2 <<<GN / 16, 256, 0, stream>>>(adj, xpt, s_src, s_dst, Dkey, out);
}

// Round 5
// 434.172 us; speedup vs baseline: 1.5169x; 1.0376x over previous
//
#include <hip/hip_runtime.h>
#include <hip/hip_bf16.h>
#include <stdint.h>

#define GN 8192
#define GF 128
#define NEG_SLOPE 0.2f
#define BIGM 700.0f       // exp(-700) == 0.0f: masked entries vanish exactly
#define PST 132           // P-tile LDS row stride (shorts)

typedef __attribute__((ext_vector_type(8))) short bf16x8;
typedef __attribute__((ext_vector_type(4))) float f32x4;

__device__ __forceinline__ unsigned fkey(float f) {
    unsigned u = __float_as_uint(f);
    return (u & 0x80000000u) ? ~u : (u | 0x80000000u);
}
__device__ __forceinline__ float funkey(unsigned k) {
    unsigned b = (k & 0x80000000u) ? (k & 0x7FFFFFFFu) : ~k;
    return __uint_as_float(b);
}
__device__ __forceinline__ unsigned short bf16rne(float f) {
    unsigned u = __float_as_uint(f);
    return (unsigned short)((u + 0x7FFFu + ((u >> 16) & 1u)) >> 16);
}
// pack two fp32 -> two bf16 (round-half-up) in one v_perm
__device__ __forceinline__ unsigned packbf(float lo, float hi) {
    return __builtin_amdgcn_perm(__float_as_uint(hi) + 0x8000u,
                                 __float_as_uint(lo) + 0x8000u, 0x07060302u);
}

// K1: x' = x@W + b (fp32); writes XPT = x'^T as bf16 [GF][GN], s_src, s_dst.
__global__ __launch_bounds__(256) void gat_k1(
    const float* __restrict__ x, const float* __restrict__ w,
    const float* __restrict__ bias, const float* __restrict__ phi,
    unsigned short* __restrict__ xpt, float* __restrict__ s_src,
    float* __restrict__ s_dst)
{
    __shared__ float Xl[16][132];
    __shared__ float Wl[32][132];
    __shared__ unsigned short TR[128][24];
    const int tid = threadIdx.x;
    const int i0 = blockIdx.x * 16;

    #pragma unroll
    for (int q = 0; q < 2; q++) {                 // stage 16x128 x tile
        int flat = (q * 256 + tid) * 4;
        int r = flat >> 7, c = flat & 127;
        *(float4*)&Xl[r][c] = *(const float4*)&x[(size_t)(i0 + r) * GF + c];
    }

    const int rid = tid >> 5;          // 0..7 -> rows 2rid, 2rid+1
    const int c0  = (tid & 31) * 4;    // 4 consecutive features

    float acc[2][4] = {};
    for (int kc = 0; kc < 4; kc++) {   // W staged in 32-row chunks
        __syncthreads();
        #pragma unroll
        for (int q = 0; q < 4; q++) {
            int flat = (q * 256 + tid) * 4;
            int kk = flat >> 7, c = flat & 127;
            *(float4*)&Wl[kk][c] = *(const float4*)&w[(size_t)(kc * 32 + kk) * GF + c];
        }
        __syncthreads();
        #pragma unroll
        for (int k = 0; k < 32; k++) {
            float4 wv = *(const float4*)&Wl[k][c0];
            #pragma unroll
            for (int m = 0; m < 2; m++) {
                float xv = Xl[rid * 2 + m][kc * 32 + k];
                acc[m][0] = fmaf(xv, wv.x, acc[m][0]);
                acc[m][1] = fmaf(xv, wv.y, acc[m][1]);
                acc[m][2] = fmaf(xv, wv.z, acc[m][2]);
                acc[m][3] = fmaf(xv, wv.w, acc[m][3]);
            }
        }
    }

    float b4[4], p1[4], p2[4];
    #pragma unroll
    for (int q = 0; q < 4; q++) {
        b4[q] = bias[c0 + q];
        p1[q] = phi[c0 + q];
        p2[q] = phi[GF + c0 + q];
    }
    #pragma unroll
    for (int m = 0; m < 2; m++) {
        float ps = 0.f, pd = 0.f;
        #pragma unroll
        for (int q = 0; q < 4; q++) {
            float v = acc[m][q] + b4[q];
            ps = fmaf(v, p1[q], ps);
            pd = fmaf(v, p2[q], pd);
            TR[c0 + q][rid * 2 + m] = bf16rne(v);   // LDS transpose staging
        }
        #pragma unroll
        for (int s = 16; s >= 1; s >>= 1) {
            ps += __shfl_xor(ps, s, 64);
            pd += __shfl_xor(pd, s, 64);
        }
        if ((tid & 31) == 0) {
            s_src[i0 + rid * 2 + m] = ps;
            s_dst[i0 + rid * 2 + m] = pd;
        }
    }
    __syncthreads();
    {   // coalesced transposed store
        const int f = tid >> 1, part = (tid & 1) * 8;
        uint2 lo = *(const uint2*)&TR[f][part];
        uint2 hi = *(const uint2*)&TR[f][part + 4];
        uint4 o; o.x = lo.x; o.y = lo.y; o.z = hi.x; o.w = hi.y;
        *(uint4*)&xpt[(size_t)f * GN + i0 + part] = o;
    }
}

// K1b: D = max(s_dst). 8 blocks -> only 8 same-address atomics.
__global__ __launch_bounds__(256) void gat_k1b(
    const float* __restrict__ s_dst, unsigned* __restrict__ Dkey)
{
    __shared__ float sm[4];
    const int tid = threadIdx.x;
    const int idx = (blockIdx.x * 256 + tid) * 4;
    float4 v = *(const float4*)&s_dst[idx];
    float m = fmaxf(fmaxf(v.x, v.y), fmaxf(v.z, v.w));
    #pragma unroll
    for (int s = 32; s >= 1; s >>= 1) m = fmaxf(m, __shfl_xor(m, s, 64));
    if ((tid & 63) == 0) sm[tid >> 6] = m;
    __syncthreads();
    if (tid == 0) {
        m = fmaxf(fmaxf(sm[0], sm[1]), fmaxf(sm[2], sm[3]));
        atomicMax(Dkey, fkey(m));
    }
}

// K2: flash GAT, coalesced adj + per-wave LDS P-transpose + register B-frags.
// Block = 16 rows, 4 waves; wave w owns 64-col chunks ck = 4t+w (32 iters).
// P phase: lane (q4,m16) covers rows {i0+4h+q4}, cols m16*4..+3 — adj loads are
// 256 B/row contiguous. P -> per-wave LDS tile -> MFMA A-frags (no barriers).
// All 16 B-frags issued BEFORE the next-chunk adj prefetch so vmcnt waits for
// B leave the adj loads in flight through the MFMA phase.
__global__ __launch_bounds__(256, 2) void gat_k2(
    const float* __restrict__ adj, const unsigned short* __restrict__ xpt,
    const float* __restrict__ s_src, const float* __restrict__ s_dst,
    const unsigned* __restrict__ Dkey, float* __restrict__ out)
{
    __shared__ float smem[8448];               // K-loop: s_dst copy; epilogue: Ol[4][16][132]
    __shared__ unsigned short Pl[4][16 * PST]; // per-wave private P tiles
    __shared__ float Zl[4][16];

    const int tid  = threadIdx.x;
    const int wave = tid >> 6, lane = tid & 63;
    const int m16  = lane & 15, q4 = lane >> 4;
    const int i0   = blockIdx.x * 16;

    #pragma unroll
    for (int s = 0; s < 8; s++) {    // stage all of s_dst into LDS (32 KB)
        const int idx = (s * 256 + tid) * 4;
        *(float4*)&smem[idx] = *(const float4*)&s_dst[idx];
    }

    const float D = funkey(*Dkey);
    float si4[4], mneg4[4];          // per-lane softmax state for rows i0+4h+q4
    #pragma unroll
    for (int h = 0; h < 4; h++) {
        const float s = s_src[i0 + h * 4 + q4];
        si4[h] = s;
        const float t0 = s + D;
        mneg4[h] = -fmaxf(t0, NEG_SLOPE * t0);   // -Mi >= -(row max) bound
    }

    unsigned short* Plw = (unsigned short*)Pl[wave];
    const float* adjb = adj + (size_t)(i0 + q4) * GN + m16 * 4;

    f32x4 acc[8];
    #pragma unroll
    for (int fg = 0; fg < 8; fg++) acc[fg] = (f32x4){0.f, 0.f, 0.f, 0.f};
    float z4[4] = {0.f, 0.f, 0.f, 0.f};

    __syncthreads();                 // s_dst LDS visible to all waves

    float4 apf[4];                   // prologue: adj prefetch for chunk t=0
    #pragma unroll
    for (int h = 0; h < 4; h++)
        apf[h] = *(const float4*)(adjb + (size_t)h * 4 * GN + wave * 64);

    #pragma unroll 1
    for (int t = 0; t < 32; t++) {
        const int cbase = (t * 4 + wave) * 64;

        // s_dst slice for these 4 cols (LDS, broadcast across q4 groups)
        const float4 d4 = *(const float4*)&smem[cbase + m16 * 4];

        #pragma unroll
        for (int h = 0; h < 4; h++) {            // P: row i0+4h+q4, cols m16*4..+3
            const float4 a = apf[h];
            const float si = si4[h], mneg = mneg4[h];
            const int irh = i0 + h * 4 + q4;
            float p[4];
            #pragma unroll
            for (int q = 0; q < 4; q++) {
                const float tt = si + (&d4.x)[q];
                const float lr = fmaxf(tt, NEG_SLOPE * tt);
                float zz = fmaf((&a.x)[q], BIGM, lr + (mneg - BIGM));
                if (cbase + m16 * 4 + q == irh) zz = lr + mneg;  // self-loop
                p[q] = __expf(zz);
            }
            z4[h] += (p[0] + p[1]) + (p[2] + p[3]);
            *(uint2*)&Plw[(h * 4 + q4) * PST + m16 * 4] =
                make_uint2(packbf(p[0], p[1]), packbf(p[2], p[3]));
        }

        // A-frags from own-wave LDS tile (lgkmcnt only, no barrier)
        const bf16x8 af0 = *(const bf16x8*)&Plw[m16 * PST + q4 * 8];
        const bf16x8 af1 = *(const bf16x8*)&Plw[m16 * PST + 32 + q4 * 8];

        // all 16 B-frags for this chunk (L2-resident xpt)
        bf16x8 B0[8], B1[8];
        const unsigned short* xb = xpt + (size_t)m16 * GN + cbase + q4 * 8;
        #pragma unroll
        for (int fg = 0; fg < 8; fg++) {
            B0[fg] = *(const bf16x8*)(xb + (size_t)(fg * 16) * GN);
            B1[fg] = *(const bf16x8*)(xb + (size_t)(fg * 16) * GN + 32);
        }

        // next-chunk adj prefetch — issued AFTER the B loads so B's vmcnt
        // waits leave these in flight through the MFMA phase
        if (t < 31) {
            const int nb = (t * 4 + 4 + wave) * 64;
            #pragma unroll
            for (int h = 0; h < 4; h++)
                apf[h] = *(const float4*)(adjb + (size_t)h * 4 * GN + nb);
        }
        __builtin_amdgcn_sched_barrier(0);   // pin issue order: B, apf, then MFMA

        #pragma unroll
        for (int fg = 0; fg < 8; fg++)
            acc[fg] = __builtin_amdgcn_mfma_f32_16x16x32_bf16(af0, B0[fg], acc[fg], 0, 0, 0);
        #pragma unroll
        for (int fg = 0; fg < 8; fg++)
            acc[fg] = __builtin_amdgcn_mfma_f32_16x16x32_bf16(af1, B1[fg], acc[fg], 0, 0, 0);
    }

    // Z: reduce z4 across the 16 m16-lanes (same q4 => same row set)
    #pragma unroll
    for (int s = 1; s <= 8; s <<= 1)
        #pragma unroll
        for (int h = 0; h < 4; h++) z4[h] += __shfl_xor(z4[h], s, 64);

    __syncthreads();                 // all waves done reading s_dst LDS
    // epilogue: reuse smem as Ol[4][16][132]; C layout col=lane&15, row=q4*4+v
    #pragma unroll
    for (int fg = 0; fg < 8; fg++)
        #pragma unroll
        for (int v = 0; v < 4; v++)
            smem[(wave * 16 + q4 * 4 + v) * 132 + fg * 16 + m16] = acc[fg][v];

    if (m16 == 0) {
        #pragma unroll
        for (int h = 0; h < 4; h++) Zl[wave][h * 4 + q4] = z4[h];
    }
    __syncthreads();

    {   // cross-wave reduce + normalize: thread -> row tid>>4, 8 cols
        const int r = tid >> 4, c = (tid & 15) * 8;
        const float invz = 1.0f / (Zl[0][r] + Zl[1][r] + Zl[2][r] + Zl[3][r]);
        f32x4 s0 = {0.f, 0.f, 0.f, 0.f}, s1 = {0.f, 0.f, 0.f, 0.f};
        #pragma unroll
        for (int wv = 0; wv < 4; wv++) {
            s0 += *(const f32x4*)&smem[(wv * 16 + r) * 132 + c];
            s1 += *(const f32x4*)&smem[(wv * 16 + r) * 132 + c + 4];
        }
        s0 *= invz; s1 *= invz;
        *(f32x4*)&out[(size_t)(i0 + r) * GF + c]     = s0;
        *(f32x4*)&out[(size_t)(i0 + r) * GF + c + 4] = s1;
    }
}

extern "C" void kernel_launch(void* const* d_in, const int* in_sizes, int n_in,
                              void* d_out, int out_size, void* d_ws, size_t ws_size,
                              hipStream_t stream)
{
    (void)in_sizes; (void)n_in; (void)out_size; (void)ws_size;
    const float* adj  = (const float*)d_in[0];
    const float* x    = (const float*)d_in[1];
    const float* w    = (const float*)d_in[2];
    const float* bias = (const float*)d_in[3];
    const float* phi  = (const float*)d_in[4];
    float* out = (float*)d_out;

    char* ws = (char*)d_ws;
    unsigned short* xpt = (unsigned short*)ws;             // 2 MB bf16 x'^T [GF][GN]
    float* s_src = (float*)(ws + (size_t)GF * GN * 2);     // 32 KB
    float* s_dst = s_src + GN;                             // 32 KB
    unsigned* Dkey = (unsigned*)(s_dst + GN);              // 4 B

    hipMemsetAsync(Dkey, 0, sizeof(unsigned), stream);
    gat_k1 <<<GN / 16, 256, 0, stream>>>(x, w, bias, phi, xpt, s_src, s_dst);
    gat_k1b<<<8, 256, 0, stream>>>(s_dst, Dkey);
    gat_k2 <<<GN / 16, 256, 0, stream>>>(adj, xpt, s_src, s_dst, Dkey, out);
}